// Round 5
// baseline (390.522 us; speedup 1.0000x reference)
//
#include <hip/hip_runtime.h>
#include <hip/hip_fp16.h>
#include <math.h>

#define EMBED   128
#define NHEADS  8
#define NPOINTS 4
#define HD      16
#define HSP     51
#define WSP     102
#define NPIX    (HSP * WSP)   // 5202
#define NQ      10000
#define NLVL    50
#define TAU     2.0e-4f       // argmax ambiguity threshold (fp16 logit err ~2e-5 std)

// ---------------------------------------------------------------------------
// Fused prep kernel. 256 threads/block:
//   blocks [0, 2601)         : value projection -> fp16 per-head layout + g-field
//   blocks [2601, 2601+5000) : offsets + attention softmax (2 queries/block)
//   block  2601+5000         : u = W_out @ W_proj
// g[h][pix] = sum_c v_f32[h][pix][c] * u[h*16+c]  (f32 — exact logit source)
// ---------------------------------------------------------------------------
#define NPB_A ((NPIX + 1) / 2)   // 2601
#define NPB_B (NQ / 2)           // 5000

__global__ __launch_bounds__(256) void k_prep(
    const float* __restrict__ value,
    const float* __restrict__ Wv,
    const float* __restrict__ bv,
    const float* __restrict__ query,
    const float* __restrict__ Woff,
    const float* __restrict__ boff,
    const float* __restrict__ Wattn,
    const float* __restrict__ battn,
    const float* __restrict__ Wout,
    const float* __restrict__ Wproj,
    __half* __restrict__ vh,        // (8, NPIX, 16) fp16
    float* __restrict__ gfield,     // (8, NPIX) f32
    float* __restrict__ off_out,
    float* __restrict__ aw_out,
    float* __restrict__ u_out) {
    const int b = blockIdx.x;
    const int t = threadIdx.x;
    const int unit = t >> 7;      // 0 or 1
    const int tt = t & 127;

    if (b < NPB_A) {  // ---- value projection + fp16 pack + g ----
        __shared__ float vrow[2][EMBED];
        __shared__ float gprod[2][EMBED];
        const int pix = b * 2 + unit;
        vrow[unit][tt] = value[(size_t)pix * EMBED + tt];
        __syncthreads();
        float acc = bv[tt];
        const float* vr = vrow[unit];
#pragma unroll 8
        for (int k = 0; k < EMBED; ++k)
            acc = fmaf(vr[k], Wv[(size_t)k * EMBED + tt], acc);
        // u_tt = Wout[tt,:] . Wproj  (recomputed per block; deterministic)
        float ut = 0.f;
#pragma unroll 8
        for (int d = 0; d < EMBED; ++d)
            ut = fmaf(Wout[(size_t)tt * EMBED + d], Wproj[d], ut);
        const int h = tt >> 4, c = tt & 15;
        vh[((size_t)h * NPIX + pix) * HD + c] = __float2half(acc);
        gprod[unit][tt] = acc * ut;
        __syncthreads();
        if (t < 16) {
            const int u2 = t >> 3, h2 = t & 7;
            float s = 0.f;
#pragma unroll
            for (int c2 = 0; c2 < HD; ++c2)
                s += gprod[u2][h2 * HD + c2];
            gfield[(size_t)h2 * NPIX + b * 2 + u2] = s;
        }
    } else if (b < NPB_A + NPB_B) {  // ---- offsets + attention ----
        const int q = (b - NPB_A) * 2 + unit;
        __shared__ float qrow[2][EMBED];
        __shared__ float attn[2][32];
        qrow[unit][tt] = query[(size_t)q * EMBED + tt];
        __syncthreads();
        const float* qr = qrow[unit];
        if (tt < 64) {
            float acc = boff[tt];
#pragma unroll 8
            for (int k = 0; k < EMBED; ++k)
                acc = fmaf(qr[k], Woff[(size_t)k * 64 + tt], acc);
            off_out[(size_t)q * 64 + tt] = acc;
        } else if (tt < 96) {
            const int j = tt - 64;
            float acc = battn[j];
#pragma unroll 8
            for (int k = 0; k < EMBED; ++k)
                acc = fmaf(qr[k], Wattn[(size_t)k * 32 + j], acc);
            attn[unit][j] = acc;
        }
        __syncthreads();
        if (tt < NHEADS) {
            const float a0 = attn[unit][tt * 4 + 0], a1 = attn[unit][tt * 4 + 1];
            const float a2 = attn[unit][tt * 4 + 2], a3 = attn[unit][tt * 4 + 3];
            const float mx = fmaxf(fmaxf(a0, a1), fmaxf(a2, a3));
            const float e0 = __expf(a0 - mx), e1 = __expf(a1 - mx);
            const float e2 = __expf(a2 - mx), e3 = __expf(a3 - mx);
            const float inv = 1.f / (e0 + e1 + e2 + e3);
            aw_out[(size_t)q * 32 + tt * 4 + 0] = e0 * inv;
            aw_out[(size_t)q * 32 + tt * 4 + 1] = e1 * inv;
            aw_out[(size_t)q * 32 + tt * 4 + 2] = e2 * inv;
            aw_out[(size_t)q * 32 + tt * 4 + 3] = e3 * inv;
        }
    } else {  // ---- u = W_out @ W_proj ----
        if (unit == 0) {
            float acc = 0.f;
#pragma unroll 8
            for (int d = 0; d < EMBED; ++d)
                acc = fmaf(Wout[(size_t)tt * EMBED + d], Wproj[d], acc);
            u_out[tt] = acc;
        }
    }
}

// ---------------------------------------------------------------------------
// Main kernel. 1 query per 256-block, 4 waves/query (levels l = 4i+w).
// Lane = h*8 + xc*4 + c4: head h, x-corner xc, channel group c4 (4 channels).
// fp16 value table: x-pair = one 64B segment, 8 lanes coalesced per head.
// Top-2 logit tracking; ambiguous queries appended to a fixup list.
// ---------------------------------------------------------------------------
__global__ __launch_bounds__(256, 8) void k_main(
    const float* __restrict__ query,
    const float* __restrict__ refp,   // (NLVL, NQ, 2)
    const float* __restrict__ voff,   // (NQ, 8, 4, 2)
    const float* __restrict__ vaw,    // (NQ, 8, 4)
    const __half* __restrict__ vh,    // (8, NPIX, 16) fp16
    const float* __restrict__ uvec,   // (128)
    const float* __restrict__ Wout,   // (128, 128)
    const float* __restrict__ bout,   // (128)
    float* __restrict__ out0,         // (NQ, 128)
    float* __restrict__ out1,         // (NQ)
    int* __restrict__ cnt,
    int* __restrict__ list) {
    const int t = threadIdx.x;
    const int w = t >> 6;             // wave 0..3
    const int lane = t & 63;
    const int h  = lane >> 3;
    const int xc = (lane >> 2) & 1;
    const int c4 = lane & 3;
    const int q = blockIdx.x;

    __shared__ float  s_rpy[NLVL];
    __shared__ float4 s_pub[3][32];
    __shared__ float  s_ms[3], s_m2s[3], s_zs[3];
    __shared__ int    s_bs[3];
    __shared__ float4 s_sv[32];

    if (t < NLVL) s_rpy[t] = refp[((size_t)t * NQ + q) * 2 + 1];

    const float4 o01 = *(const float4*)(voff + (size_t)q * 64 + h * 8);
    const float4 o23 = *(const float4*)(voff + (size_t)q * 64 + h * 8 + 4);
    const float4 aw4 = *(const float4*)(vaw + (size_t)q * 32 + h * 4);
    const float4 u4  = *(const float4*)(uvec + h * 16 + c4 * 4);
    const float rpx = refp[(size_t)q * 2];

    const float offx[4] = {o01.x, o01.z, o23.x, o23.z};
    const float offy[4] = {o01.y, o01.w, o23.y, o23.w};
    const float aww[4]  = {aw4.x, aw4.y, aw4.z, aw4.w};

    // level-independent x state: this lane's x-corner weight & pixel, per point
    float wlx[NPOINTS], oyc[NPOINTS];
    int xpix[NPOINTS];
#pragma unroll
    for (int p = 0; p < NPOINTS; ++p) {
        const float px = fmaf(rpx, (float)WSP, offx[p]) - 0.5f;
        const float fx = floorf(px);
        const float dx = px - fx;
        const int xi = (int)fx + xc;
        const float wx = xc ? dx : (1.f - dx);
        wlx[p] = ((unsigned)xi < (unsigned)WSP) ? aww[p] * wx : 0.f;
        xpix[p] = min(max(xi, 0), WSP - 1);
        oyc[p] = offy[p] - 0.5f;
    }
    const __half* vbase = vh + (size_t)h * NPIX * HD + c4 * 4;

    __syncthreads();

    float4 acc = {0.f, 0.f, 0.f, 0.f};
    float Z = 0.f, m = -1e30f, m2 = -1e30f;
    int best = 0;

#pragma unroll 1
    for (int i = 0; i < 13; ++i) {
        const int l = 4 * i + w;
        if (l >= NLVL) break;         // wave-uniform (w)
        const float rpy = s_rpy[l];
        float4 s = {0.f, 0.f, 0.f, 0.f};
#pragma unroll
        for (int p = 0; p < NPOINTS; ++p) {
            const float py = fmaf(rpy, (float)HSP, oyc[p]);
            const float fy = floorf(py);
            const float dy = py - fy;
            const int y0 = (int)fy;
            const float t0 = ((unsigned)y0 < (unsigned)HSP) ? (1.f - dy) : 0.f;
            const float t1 = ((unsigned)(y0 + 1) < (unsigned)HSP) ? dy : 0.f;
            const int rb0 = min(max(y0, 0), HSP - 1) * WSP;
            const int rb1 = min(max(y0 + 1, 0), HSP - 1) * WSP;
            const float w0 = wlx[p] * t0;
            const float w1 = wlx[p] * t1;
            const __half2* p0 = (const __half2*)(vbase + (size_t)(rb0 + xpix[p]) * HD);
            const __half2* p1 = (const __half2*)(vbase + (size_t)(rb1 + xpix[p]) * HD);
            const __half2 h00 = p0[0], h01 = p0[1];
            const __half2 h10 = p1[0], h11 = p1[1];
            const float2 a0 = __half22float2(h00);
            const float2 a1 = __half22float2(h01);
            const float2 b0 = __half22float2(h10);
            const float2 b1 = __half22float2(h11);
            s.x = fmaf(w0, a0.x, s.x); s.y = fmaf(w0, a0.y, s.y);
            s.z = fmaf(w0, a1.x, s.z); s.w = fmaf(w0, a1.y, s.w);
            s.x = fmaf(w1, b0.x, s.x); s.y = fmaf(w1, b0.y, s.y);
            s.z = fmaf(w1, b1.x, s.z); s.w = fmaf(w1, b1.y, s.w);
        }
        // logit: full-wave reduction (covers both x-corners + all heads/chans)
        float part = s.x * u4.x;
        part = fmaf(s.y, u4.y, part);
        part = fmaf(s.z, u4.z, part);
        part = fmaf(s.w, u4.w, part);
#pragma unroll
        for (int d = 1; d < 64; d <<= 1)
            part += __shfl_xor(part, d, 64);
        const float e = __expf(part);
        Z += e;
        acc.x = fmaf(e, s.x, acc.x);
        acc.y = fmaf(e, s.y, acc.y);
        acc.z = fmaf(e, s.z, acc.z);
        acc.w = fmaf(e, s.w, acc.w);
        if (part > m) { m2 = m; m = part; best = l; }
        else          { m2 = fmaxf(m2, part); }
    }

    // merge x-corner partials (lanes differ in bit 2)
    acc.x += __shfl_xor(acc.x, 4, 64);
    acc.y += __shfl_xor(acc.y, 4, 64);
    acc.z += __shfl_xor(acc.z, 4, 64);
    acc.w += __shfl_xor(acc.w, 4, 64);

    // waves 1..3 publish; wave 0 merges
    if (w > 0) {
        if (xc == 0) s_pub[w - 1][h * 4 + c4] = acc;
        if (lane == 0) {
            s_ms[w - 1] = m; s_m2s[w - 1] = m2;
            s_zs[w - 1] = Z; s_bs[w - 1] = best;
        }
    }
    __syncthreads();

    if (w == 0) {
        const int hc = h * 4 + c4;
#pragma unroll
        for (int j = 0; j < 3; ++j) {
            const float4 ao = s_pub[j][hc];
            const float mo = s_ms[j], m2o = s_m2s[j], Zo = s_zs[j];
            const int bo = s_bs[j];
            const bool takeOther = (mo > m) || (mo == m && bo < best);
            m2 = fmaxf(fmaxf(m2, m2o), fminf(m, mo));
            best = takeOther ? bo : best;
            m = fmaxf(m, mo);
            Z += Zo;
            acc.x += ao.x; acc.y += ao.y; acc.z += ao.z; acc.w += ao.w;
        }
        const float inv = 1.f / Z;
        if (xc == 0) {
            float4 sv;
            sv.x = acc.x * inv; sv.y = acc.y * inv;
            sv.z = acc.z * inv; sv.w = acc.w * inv;
            s_sv[hc] = sv;
        }
        if (lane == 0) {
            out1[q] = (float)best;
            if (m - m2 < TAU) {             // ambiguous under fp16 noise -> fixup
                const int ii = atomicAdd(cnt, 1);
                list[ii] = q;
            }
        }
        // epilogue: out[dp] = sum_c s[c]*Wout[c][dp] + bout[dp] + 2*query[q][dp]
        const int sub = lane & 31;
        const int half = lane >> 5;
        const int dpb = sub * 4;
        float4 r = {0.f, 0.f, 0.f, 0.f};
        if (half == 0) {
            const float4 b4 = *(const float4*)(bout + dpb);
            const float4 q4 = *(const float4*)(query + (size_t)q * EMBED + dpb);
            r.x = fmaf(2.f, q4.x, b4.x);
            r.y = fmaf(2.f, q4.y, b4.y);
            r.z = fmaf(2.f, q4.z, b4.z);
            r.w = fmaf(2.f, q4.w, b4.w);
        }
        const int cg0 = half * 16;
#pragma unroll 4
        for (int cg = cg0; cg < cg0 + 16; ++cg) {
            const float4 s4 = s_sv[cg];
            const float4 w0 = *(const float4*)(Wout + (size_t)(cg * 4 + 0) * EMBED + dpb);
            const float4 w1 = *(const float4*)(Wout + (size_t)(cg * 4 + 1) * EMBED + dpb);
            const float4 w2v = *(const float4*)(Wout + (size_t)(cg * 4 + 2) * EMBED + dpb);
            const float4 w3 = *(const float4*)(Wout + (size_t)(cg * 4 + 3) * EMBED + dpb);
            r.x = fmaf(s4.x, w0.x, r.x); r.y = fmaf(s4.x, w0.y, r.y);
            r.z = fmaf(s4.x, w0.z, r.z); r.w = fmaf(s4.x, w0.w, r.w);
            r.x = fmaf(s4.y, w1.x, r.x); r.y = fmaf(s4.y, w1.y, r.y);
            r.z = fmaf(s4.y, w1.z, r.z); r.w = fmaf(s4.y, w1.w, r.w);
            r.x = fmaf(s4.z, w2v.x, r.x); r.y = fmaf(s4.z, w2v.y, r.y);
            r.z = fmaf(s4.z, w2v.z, r.z); r.w = fmaf(s4.z, w2v.w, r.w);
            r.x = fmaf(s4.w, w3.x, r.x); r.y = fmaf(s4.w, w3.y, r.y);
            r.z = fmaf(s4.w, w3.z, r.z); r.w = fmaf(s4.w, w3.w, r.w);
        }
        {
            const float rx = __shfl_xor(r.x, 32, 64);
            const float ry = __shfl_xor(r.y, 32, 64);
            const float rz = __shfl_xor(r.z, 32, 64);
            const float rw = __shfl_xor(r.w, 32, 64);
            r.x += rx; r.y += ry; r.z += rz; r.w += rw;
        }
        if (half == 0)
            *(float4*)(out0 + (size_t)q * EMBED + dpb) = r;
    }
}

// ---------------------------------------------------------------------------
// Exact-f32 argmax fixup for flagged queries. One 64-thread block handles one
// flagged query per grid-stride step; lane = level. Logits via the g-field:
// logit_l = sum_{h,p} aw * bilinear(g_h)  ==  (exact) samp_agg . u
// ---------------------------------------------------------------------------
__global__ __launch_bounds__(64) void k_fix(
    const float* __restrict__ refp,
    const float* __restrict__ voff,
    const float* __restrict__ vaw,
    const float* __restrict__ gfield,  // (8, NPIX)
    const int* __restrict__ cnt,
    const int* __restrict__ list,
    float* __restrict__ out1) {
    const int n = *cnt;
    const int lane = threadIdx.x;
    for (int idx = blockIdx.x; idx < n; idx += gridDim.x) {
        const int q = list[idx];
        float logit = -1e30f;
        if (lane < NLVL) {
            const float rpx = refp[(size_t)q * 2];
            const float rpy = refp[((size_t)lane * NQ + q) * 2 + 1];
            float accl = 0.f;
            for (int h = 0; h < NHEADS; ++h) {
                const float4 o01 = *(const float4*)(voff + (size_t)q * 64 + h * 8);
                const float4 o23 = *(const float4*)(voff + (size_t)q * 64 + h * 8 + 4);
                const float4 aw4 = *(const float4*)(vaw + (size_t)q * 32 + h * 4);
                const float* gh = gfield + (size_t)h * NPIX;
                const float offx[4] = {o01.x, o01.z, o23.x, o23.z};
                const float offy[4] = {o01.y, o01.w, o23.y, o23.w};
                const float aww[4]  = {aw4.x, aw4.y, aw4.z, aw4.w};
#pragma unroll
                for (int p = 0; p < NPOINTS; ++p) {
                    const float px = fmaf(rpx, (float)WSP, offx[p]) - 0.5f;
                    const float py = fmaf(rpy, (float)HSP, offy[p]) - 0.5f;
                    const float fx = floorf(px), fy = floorf(py);
                    const float dx = px - fx, dy = py - fy;
                    const int x0 = (int)fx, y0 = (int)fy;
                    const float wx0 = ((unsigned)x0 < (unsigned)WSP) ? (1.f - dx) : 0.f;
                    const float wx1 = ((unsigned)(x0 + 1) < (unsigned)WSP) ? dx : 0.f;
                    const float t0 = ((unsigned)y0 < (unsigned)HSP) ? (1.f - dy) : 0.f;
                    const float t1 = ((unsigned)(y0 + 1) < (unsigned)HSP) ? dy : 0.f;
                    const int xc0 = min(max(x0, 0), WSP - 1);
                    const int xc1 = min(max(x0 + 1, 0), WSP - 1);
                    const int rb0 = min(max(y0, 0), HSP - 1) * WSP;
                    const int rb1 = min(max(y0 + 1, 0), HSP - 1) * WSP;
                    const float g00 = gh[rb0 + xc0];
                    const float g01 = gh[rb0 + xc1];
                    const float g10 = gh[rb1 + xc0];
                    const float g11 = gh[rb1 + xc1];
                    const float bil = wx0 * t0 * g00 + wx1 * t0 * g01
                                    + wx0 * t1 * g10 + wx1 * t1 * g11;
                    accl = fmaf(aww[p], bil, accl);
                }
            }
            logit = accl;
        }
        float v = logit;
        int b = lane;
#pragma unroll
        for (int d = 1; d < 64; d <<= 1) {
            const float vo = __shfl_xor(v, d, 64);
            const int bo = __shfl_xor(b, d, 64);
            if ((vo > v) || (vo == v && bo < b)) { v = vo; b = bo; }
        }
        if (lane == 0) out1[q] = (float)b;
    }
}

// ---------------------------------------------------------------------------
extern "C" void kernel_launch(void* const* d_in, const int* in_sizes, int n_in,
                              void* d_out, int out_size, void* d_ws, size_t ws_size,
                              hipStream_t stream) {
    const float* query = (const float*)d_in[0];
    const float* value = (const float*)d_in[1];
    const float* refp  = (const float*)d_in[2];
    const float* Woff  = (const float*)d_in[3];
    const float* boff  = (const float*)d_in[4];
    const float* Wattn = (const float*)d_in[5];
    const float* battn = (const float*)d_in[6];
    const float* Wval  = (const float*)d_in[7];
    const float* bval  = (const float*)d_in[8];
    const float* Wout  = (const float*)d_in[9];
    const float* bout  = (const float*)d_in[10];
    const float* Wproj = (const float*)d_in[11];
    // d_in[12] = b_proj: level-constant -> cancels in softmax/argmax, unused.

    float* ws = (float*)d_ws;
    __half* ws_vh = (__half*)ws;                          // 8*5202*16 halves
    float* ws_g   = ws + ((size_t)NHEADS * NPIX * HD + 1) / 2;  // 8*5202 f
    float* ws_off = ws_g + (size_t)NHEADS * NPIX;         // NQ*64
    float* ws_aw  = ws_off + (size_t)NQ * 64;             // NQ*32
    float* ws_u   = ws_aw + (size_t)NQ * 32;              // 128
    int*   ws_cnt = (int*)(ws_u + 128);                   // 1
    int*   ws_list = ws_cnt + 1;                          // NQ

    float* out0 = (float*)d_out;
    float* out1 = out0 + (size_t)NQ * EMBED;

    hipMemsetAsync(ws_cnt, 0, sizeof(int), stream);
    hipLaunchKernelGGL(k_prep, dim3(NPB_A + NPB_B + 1), dim3(256), 0, stream,
                       value, Wval, bval, query, Woff, boff, Wattn, battn,
                       Wout, Wproj, ws_vh, ws_g, ws_off, ws_aw, ws_u);
    hipLaunchKernelGGL(k_main, dim3(NQ), dim3(256), 0, stream,
                       query, refp, ws_off, ws_aw, ws_vh, ws_u, Wout, bout,
                       out0, out1, ws_cnt, ws_list);
    hipLaunchKernelGGL(k_fix, dim3(256), dim3(64), 0, stream,
                       refp, ws_off, ws_aw, ws_g, ws_cnt, ws_list, out1);
}

// Round 6
// 372.744 us; speedup vs baseline: 1.0477x; 1.0477x over previous
//
#include <hip/hip_runtime.h>
#include <hip/hip_fp16.h>
#include <math.h>

#define EMBED   128
#define NHEADS  8
#define NPOINTS 4
#define HD      16
#define HSP     51
#define WSP     102
#define NPIX    (HSP * WSP)   // 5202
#define NQ      10000
#define NLVL    50
#define TAU     2.0e-4f       // argmax ambiguity threshold (fp16 logit err ~2e-5)

// ---------------------------------------------------------------------------
// u = W_out @ W_proj (128 floats). Runs first; k_prep and k_main consume it.
// ---------------------------------------------------------------------------
__global__ __launch_bounds__(128) void k_uvec(const float* __restrict__ Wout,
                                              const float* __restrict__ Wproj,
                                              float* __restrict__ u) {
    const int c = threadIdx.x;
    float acc = 0.f;
#pragma unroll 8
    for (int d = 0; d < EMBED; ++d)
        acc = fmaf(Wout[(size_t)c * EMBED + d], Wproj[d], acc);
    u[c] = acc;
}

// ---------------------------------------------------------------------------
// Fused prep kernel. 256 threads/block:
//   blocks [0, 2601)         : value projection -> fp16 per-head layout + g-field
//   blocks [2601, 2601+5000) : offsets + attention softmax (2 queries/block)
// g[h][pix] = sum_c v_f32[h][pix][c] * u[h*16+c]  (f32 — exact logit source)
// ---------------------------------------------------------------------------
#define NPB_A ((NPIX + 1) / 2)   // 2601
#define NPB_B (NQ / 2)           // 5000

__global__ __launch_bounds__(256) void k_prep(
    const float* __restrict__ value,
    const float* __restrict__ Wv,
    const float* __restrict__ bv,
    const float* __restrict__ query,
    const float* __restrict__ Woff,
    const float* __restrict__ boff,
    const float* __restrict__ Wattn,
    const float* __restrict__ battn,
    const float* __restrict__ uvec,
    __half* __restrict__ vh,        // (8, NPIX, 16) fp16
    float* __restrict__ gfield,     // (8, NPIX) f32
    float* __restrict__ off_out,
    float* __restrict__ aw_out) {
    const int b = blockIdx.x;
    const int t = threadIdx.x;
    const int unit = t >> 7;      // 0 or 1
    const int tt = t & 127;

    if (b < NPB_A) {  // ---- value projection + fp16 pack + g ----
        __shared__ float vrow[2][EMBED];
        __shared__ float gprod[2][EMBED];
        const int pix = b * 2 + unit;
        vrow[unit][tt] = value[(size_t)pix * EMBED + tt];
        __syncthreads();
        float acc = bv[tt];
        const float* vr = vrow[unit];
#pragma unroll 8
        for (int k = 0; k < EMBED; ++k)
            acc = fmaf(vr[k], Wv[(size_t)k * EMBED + tt], acc);
        const int h = tt >> 4, c = tt & 15;
        vh[((size_t)h * NPIX + pix) * HD + c] = __float2half(acc);
        gprod[unit][tt] = acc * uvec[tt];
        __syncthreads();
        if (t < 16) {
            const int u2 = t >> 3, h2 = t & 7;
            float s = 0.f;
#pragma unroll
            for (int c2 = 0; c2 < HD; ++c2)
                s += gprod[u2][h2 * HD + c2];
            gfield[(size_t)h2 * NPIX + b * 2 + u2] = s;
        }
    } else {  // ---- offsets + attention ----
        const int q = (b - NPB_A) * 2 + unit;
        __shared__ float qrow[2][EMBED];
        __shared__ float attn[2][32];
        qrow[unit][tt] = query[(size_t)q * EMBED + tt];
        __syncthreads();
        const float* qr = qrow[unit];
        if (tt < 64) {
            float acc = boff[tt];
#pragma unroll 8
            for (int k = 0; k < EMBED; ++k)
                acc = fmaf(qr[k], Woff[(size_t)k * 64 + tt], acc);
            off_out[(size_t)q * 64 + tt] = acc;
        } else if (tt < 96) {
            const int j = tt - 64;
            float acc = battn[j];
#pragma unroll 8
            for (int k = 0; k < EMBED; ++k)
                acc = fmaf(qr[k], Wattn[(size_t)k * 32 + j], acc);
            attn[unit][j] = acc;
        }
        __syncthreads();
        if (tt < NHEADS) {
            const float a0 = attn[unit][tt * 4 + 0], a1 = attn[unit][tt * 4 + 1];
            const float a2 = attn[unit][tt * 4 + 2], a3 = attn[unit][tt * 4 + 3];
            const float mx = fmaxf(fmaxf(a0, a1), fmaxf(a2, a3));
            const float e0 = __expf(a0 - mx), e1 = __expf(a1 - mx);
            const float e2 = __expf(a2 - mx), e3 = __expf(a3 - mx);
            const float inv = 1.f / (e0 + e1 + e2 + e3);
            aw_out[(size_t)q * 32 + tt * 4 + 0] = e0 * inv;
            aw_out[(size_t)q * 32 + tt * 4 + 1] = e1 * inv;
            aw_out[(size_t)q * 32 + tt * 4 + 2] = e2 * inv;
            aw_out[(size_t)q * 32 + tt * 4 + 3] = e3 * inv;
        }
    }
}

// ---------------------------------------------------------------------------
// Main kernel. 1 query per 256-block, 4 waves/query (levels l = 4i+w).
// Lane = h*8 + yc*4 + xc*2 + c8: one 16B fp16 load per (lane, point) covers
// all 4 corners x 16 ch x 8 heads per wave instruction (4 vmem inst/level).
// Per-lane 8-channel corner-partial accumulators; corner merge deferred to
// the end (linear). Top-2 logit tracking + exact-f32 fixup list.
// ---------------------------------------------------------------------------
__global__ __launch_bounds__(256, 8) void k_main(
    const float* __restrict__ query,
    const float* __restrict__ refp,   // (NLVL, NQ, 2)
    const float* __restrict__ voff,   // (NQ, 8, 4, 2)
    const float* __restrict__ vaw,    // (NQ, 8, 4)
    const __half* __restrict__ vh,    // (8, NPIX, 16) fp16
    const float* __restrict__ uvec,   // (128)
    const float* __restrict__ Wout,   // (128, 128)
    const float* __restrict__ bout,   // (128)
    float* __restrict__ out0,         // (NQ, 128)
    float* __restrict__ out1,         // (NQ)
    int* __restrict__ cnt,
    int* __restrict__ list) {
    const int t = threadIdx.x;
    const int w = t >> 6;             // wave 0..3
    const int lane = t & 63;
    const int h  = lane >> 3;
    const int yc = (lane >> 2) & 1;
    const int xc = (lane >> 1) & 1;
    const int c8 = lane & 1;
    const int q = blockIdx.x;

    __shared__ float  s_rpy[NLVL];
    __shared__ float4 s_pub[3][32];   // [wave-1][h*4 + c8*2 + k]
    __shared__ float  s_ms[3], s_m2s[3], s_zs[3];
    __shared__ int    s_bs[3];
    __shared__ float4 s_sv[32];

    if (t < NLVL) s_rpy[t] = refp[((size_t)t * NQ + q) * 2 + 1];

    const float4 o01 = *(const float4*)(voff + (size_t)q * 64 + h * 8);
    const float4 o23 = *(const float4*)(voff + (size_t)q * 64 + h * 8 + 4);
    const float4 aw4 = *(const float4*)(vaw + (size_t)q * 32 + h * 4);
    const float4 ua = *(const float4*)(uvec + h * 16 + c8 * 8);
    const float4 ub = *(const float4*)(uvec + h * 16 + c8 * 8 + 4);
    const float rpx = refp[(size_t)q * 2];

    const float offx[4] = {o01.x, o01.z, o23.x, o23.z};
    const float offy[4] = {o01.y, o01.w, o23.y, o23.w};
    const float aww[4]  = {aw4.x, aw4.y, aw4.z, aw4.w};

    // level-independent x state: this lane's x-corner weight (incl aw) & pixel
    float wlx[NPOINTS], oyc[NPOINTS];
    int xpix[NPOINTS];
#pragma unroll
    for (int p = 0; p < NPOINTS; ++p) {
        const float px = fmaf(rpx, (float)WSP, offx[p]) - 0.5f;
        const float fx = floorf(px);
        const float dx = px - fx;
        const int xi = (int)fx + xc;
        const float wx = xc ? dx : (1.f - dx);
        wlx[p] = ((unsigned)xi < (unsigned)WSP) ? aww[p] * wx : 0.f;
        xpix[p] = min(max(xi, 0), WSP - 1);
        oyc[p] = offy[p] - 0.5f;
    }
    const __half* vb = vh + (size_t)h * NPIX * HD + c8 * 8;

    __syncthreads();

    float a0_ = 0.f, a1_ = 0.f, a2_ = 0.f, a3_ = 0.f;
    float a4_ = 0.f, a5_ = 0.f, a6_ = 0.f, a7_ = 0.f;
    float Z = 0.f, m = -1e30f, m2 = -1e30f;
    int best = 0;

#pragma unroll 1
    for (int i = 0; i < 13; ++i) {
        const int l = 4 * i + w;
        if (l >= NLVL) break;         // wave-uniform (w)
        const float rpy = s_rpy[l];
        float s0 = 0.f, s1 = 0.f, s2 = 0.f, s3 = 0.f;
        float s4 = 0.f, s5 = 0.f, s6 = 0.f, s7 = 0.f;
#pragma unroll
        for (int p = 0; p < NPOINTS; ++p) {
            const float py = fmaf(rpy, (float)HSP, oyc[p]);
            const float fy = floorf(py);
            const float dy = py - fy;
            const int yi = (int)fy + yc;
            const float wy = yc ? dy : (1.f - dy);
            const float wv = ((unsigned)yi < (unsigned)HSP) ? wy : 0.f;
            const float wgt = wlx[p] * wv;
            const int pixel = min(max(yi, 0), HSP - 1) * WSP + xpix[p];
            const float4 raw = *(const float4*)(vb + (size_t)pixel * HD);
            const __half2* hp = (const __half2*)&raw;
            const float2 f0 = __half22float2(hp[0]);
            const float2 f1 = __half22float2(hp[1]);
            const float2 f2 = __half22float2(hp[2]);
            const float2 f3 = __half22float2(hp[3]);
            s0 = fmaf(wgt, f0.x, s0); s1 = fmaf(wgt, f0.y, s1);
            s2 = fmaf(wgt, f1.x, s2); s3 = fmaf(wgt, f1.y, s3);
            s4 = fmaf(wgt, f2.x, s4); s5 = fmaf(wgt, f2.y, s5);
            s6 = fmaf(wgt, f3.x, s6); s7 = fmaf(wgt, f3.y, s7);
        }
        // logit: dot with u, full 64-lane reduce covers corners+heads+channels
        float part = s0 * ua.x;
        part = fmaf(s1, ua.y, part);
        part = fmaf(s2, ua.z, part);
        part = fmaf(s3, ua.w, part);
        part = fmaf(s4, ub.x, part);
        part = fmaf(s5, ub.y, part);
        part = fmaf(s6, ub.z, part);
        part = fmaf(s7, ub.w, part);
#pragma unroll
        for (int d = 1; d < 64; d <<= 1)
            part += __shfl_xor(part, d, 64);
        const float e = __expf(part);
        Z += e;
        a0_ = fmaf(e, s0, a0_); a1_ = fmaf(e, s1, a1_);
        a2_ = fmaf(e, s2, a2_); a3_ = fmaf(e, s3, a3_);
        a4_ = fmaf(e, s4, a4_); a5_ = fmaf(e, s5, a5_);
        a6_ = fmaf(e, s6, a6_); a7_ = fmaf(e, s7, a7_);
        if (part > m) { m2 = m; m = part; best = l; }
        else          { m2 = fmaxf(m2, part); }
    }

    // corner-merge accumulators: xc (bit1), then yc (bit2); result in all lanes
#pragma unroll
    for (int d = 2; d <= 4; d <<= 1) {
        a0_ += __shfl_xor(a0_, d, 64); a1_ += __shfl_xor(a1_, d, 64);
        a2_ += __shfl_xor(a2_, d, 64); a3_ += __shfl_xor(a3_, d, 64);
        a4_ += __shfl_xor(a4_, d, 64); a5_ += __shfl_xor(a5_, d, 64);
        a6_ += __shfl_xor(a6_, d, 64); a7_ += __shfl_xor(a7_, d, 64);
    }

    // waves 1..3 publish; wave 0 merges
    if (w > 0) {
        if ((lane & 6) == 0) {        // one lane per (h, c8)
            const int g = h * 4 + c8 * 2;
            s_pub[w - 1][g]     = make_float4(a0_, a1_, a2_, a3_);
            s_pub[w - 1][g + 1] = make_float4(a4_, a5_, a6_, a7_);
        }
        if (lane == 0) {
            s_ms[w - 1] = m; s_m2s[w - 1] = m2;
            s_zs[w - 1] = Z; s_bs[w - 1] = best;
        }
    }
    __syncthreads();

    if (w == 0) {
        const int g = h * 4 + c8 * 2;
#pragma unroll
        for (int j = 0; j < 3; ++j) {
            const float4 pa = s_pub[j][g];
            const float4 pb = s_pub[j][g + 1];
            const float mo = s_ms[j], m2o = s_m2s[j], Zo = s_zs[j];
            const int bo = s_bs[j];
            const bool takeOther = (mo > m) || (mo == m && bo < best);
            m2 = fmaxf(fmaxf(m2, m2o), fminf(m, mo));
            best = takeOther ? bo : best;
            m = fmaxf(m, mo);
            Z += Zo;
            a0_ += pa.x; a1_ += pa.y; a2_ += pa.z; a3_ += pa.w;
            a4_ += pb.x; a5_ += pb.y; a6_ += pb.z; a7_ += pb.w;
        }
        const float inv = 1.f / Z;
        if ((lane & 6) == 0) {
            s_sv[g]     = make_float4(a0_ * inv, a1_ * inv, a2_ * inv, a3_ * inv);
            s_sv[g + 1] = make_float4(a4_ * inv, a5_ * inv, a6_ * inv, a7_ * inv);
        }
        if (lane == 0) {
            out1[q] = (float)best;
            if (m - m2 < TAU) {             // ambiguous under fp16 noise -> fixup
                const int ii = atomicAdd(cnt, 1);
                list[ii] = q;
            }
        }
        // same-wave DS ordering: s_sv writes visible to wave 0's reads below

        // epilogue: out[dp] = sum_c s[c]*Wout[c][dp] + bout[dp] + 2*query[q][dp]
        const int sub = lane & 31;
        const int half = lane >> 5;
        const int dpb = sub * 4;
        float4 r = {0.f, 0.f, 0.f, 0.f};
        if (half == 0) {
            const float4 b4 = *(const float4*)(bout + dpb);
            const float4 q4 = *(const float4*)(query + (size_t)q * EMBED + dpb);
            r.x = fmaf(2.f, q4.x, b4.x);
            r.y = fmaf(2.f, q4.y, b4.y);
            r.z = fmaf(2.f, q4.z, b4.z);
            r.w = fmaf(2.f, q4.w, b4.w);
        }
        const int cg0 = half * 16;
#pragma unroll 4
        for (int cg = cg0; cg < cg0 + 16; ++cg) {
            const float4 s4 = s_sv[cg];
            const float4 w0 = *(const float4*)(Wout + (size_t)(cg * 4 + 0) * EMBED + dpb);
            const float4 w1 = *(const float4*)(Wout + (size_t)(cg * 4 + 1) * EMBED + dpb);
            const float4 w2v = *(const float4*)(Wout + (size_t)(cg * 4 + 2) * EMBED + dpb);
            const float4 w3 = *(const float4*)(Wout + (size_t)(cg * 4 + 3) * EMBED + dpb);
            r.x = fmaf(s4.x, w0.x, r.x); r.y = fmaf(s4.x, w0.y, r.y);
            r.z = fmaf(s4.x, w0.z, r.z); r.w = fmaf(s4.x, w0.w, r.w);
            r.x = fmaf(s4.y, w1.x, r.x); r.y = fmaf(s4.y, w1.y, r.y);
            r.z = fmaf(s4.y, w1.z, r.z); r.w = fmaf(s4.y, w1.w, r.w);
            r.x = fmaf(s4.z, w2v.x, r.x); r.y = fmaf(s4.z, w2v.y, r.y);
            r.z = fmaf(s4.z, w2v.z, r.z); r.w = fmaf(s4.z, w2v.w, r.w);
            r.x = fmaf(s4.w, w3.x, r.x); r.y = fmaf(s4.w, w3.y, r.y);
            r.z = fmaf(s4.w, w3.z, r.z); r.w = fmaf(s4.w, w3.w, r.w);
        }
        {
            const float rx = __shfl_xor(r.x, 32, 64);
            const float ry = __shfl_xor(r.y, 32, 64);
            const float rz = __shfl_xor(r.z, 32, 64);
            const float rw = __shfl_xor(r.w, 32, 64);
            r.x += rx; r.y += ry; r.z += rz; r.w += rw;
        }
        if (half == 0)
            *(float4*)(out0 + (size_t)q * EMBED + dpb) = r;
    }
}

// ---------------------------------------------------------------------------
// Exact-f32 argmax fixup for flagged queries (bilinear of g == exact logit).
// ---------------------------------------------------------------------------
__global__ __launch_bounds__(64) void k_fix(
    const float* __restrict__ refp,
    const float* __restrict__ voff,
    const float* __restrict__ vaw,
    const float* __restrict__ gfield,  // (8, NPIX)
    const int* __restrict__ cnt,
    const int* __restrict__ list,
    float* __restrict__ out1) {
    const int n = *cnt;
    const int lane = threadIdx.x;
    for (int idx = blockIdx.x; idx < n; idx += gridDim.x) {
        const int q = list[idx];
        float logit = -1e30f;
        if (lane < NLVL) {
            const float rpx = refp[(size_t)q * 2];
            const float rpy = refp[((size_t)lane * NQ + q) * 2 + 1];
            float accl = 0.f;
            for (int h = 0; h < NHEADS; ++h) {
                const float4 o01 = *(const float4*)(voff + (size_t)q * 64 + h * 8);
                const float4 o23 = *(const float4*)(voff + (size_t)q * 64 + h * 8 + 4);
                const float4 aw4 = *(const float4*)(vaw + (size_t)q * 32 + h * 4);
                const float* gh = gfield + (size_t)h * NPIX;
                const float offx[4] = {o01.x, o01.z, o23.x, o23.z};
                const float offy[4] = {o01.y, o01.w, o23.y, o23.w};
                const float aww[4]  = {aw4.x, aw4.y, aw4.z, aw4.w};
#pragma unroll
                for (int p = 0; p < NPOINTS; ++p) {
                    const float px = fmaf(rpx, (float)WSP, offx[p]) - 0.5f;
                    const float py = fmaf(rpy, (float)HSP, offy[p]) - 0.5f;
                    const float fx = floorf(px), fy = floorf(py);
                    const float dx = px - fx, dy = py - fy;
                    const int x0 = (int)fx, y0 = (int)fy;
                    const float wx0 = ((unsigned)x0 < (unsigned)WSP) ? (1.f - dx) : 0.f;
                    const float wx1 = ((unsigned)(x0 + 1) < (unsigned)WSP) ? dx : 0.f;
                    const float t0 = ((unsigned)y0 < (unsigned)HSP) ? (1.f - dy) : 0.f;
                    const float t1 = ((unsigned)(y0 + 1) < (unsigned)HSP) ? dy : 0.f;
                    const int xc0 = min(max(x0, 0), WSP - 1);
                    const int xc1 = min(max(x0 + 1, 0), WSP - 1);
                    const int rb0 = min(max(y0, 0), HSP - 1) * WSP;
                    const int rb1 = min(max(y0 + 1, 0), HSP - 1) * WSP;
                    const float g00 = gh[rb0 + xc0];
                    const float g01 = gh[rb0 + xc1];
                    const float g10 = gh[rb1 + xc0];
                    const float g11 = gh[rb1 + xc1];
                    const float bil = wx0 * t0 * g00 + wx1 * t0 * g01
                                    + wx0 * t1 * g10 + wx1 * t1 * g11;
                    accl = fmaf(aww[p], bil, accl);
                }
            }
            logit = accl;
        }
        float v = logit;
        int b = lane;
#pragma unroll
        for (int d = 1; d < 64; d <<= 1) {
            const float vo = __shfl_xor(v, d, 64);
            const int bo = __shfl_xor(b, d, 64);
            if ((vo > v) || (vo == v && bo < b)) { v = vo; b = bo; }
        }
        if (lane == 0) out1[q] = (float)b;
    }
}

// ---------------------------------------------------------------------------
extern "C" void kernel_launch(void* const* d_in, const int* in_sizes, int n_in,
                              void* d_out, int out_size, void* d_ws, size_t ws_size,
                              hipStream_t stream) {
    const float* query = (const float*)d_in[0];
    const float* value = (const float*)d_in[1];
    const float* refp  = (const float*)d_in[2];
    const float* Woff  = (const float*)d_in[3];
    const float* boff  = (const float*)d_in[4];
    const float* Wattn = (const float*)d_in[5];
    const float* battn = (const float*)d_in[6];
    const float* Wval  = (const float*)d_in[7];
    const float* bval  = (const float*)d_in[8];
    const float* Wout  = (const float*)d_in[9];
    const float* bout  = (const float*)d_in[10];
    const float* Wproj = (const float*)d_in[11];
    // d_in[12] = b_proj: level-constant -> cancels in softmax/argmax, unused.

    float* ws = (float*)d_ws;
    __half* ws_vh = (__half*)ws;                          // 8*5202*16 halves
    float* ws_g   = ws + ((size_t)NHEADS * NPIX * HD + 1) / 2;  // 8*5202 f
    float* ws_off = ws_g + (size_t)NHEADS * NPIX;         // NQ*64
    float* ws_aw  = ws_off + (size_t)NQ * 64;             // NQ*32
    float* ws_u   = ws_aw + (size_t)NQ * 32;              // 128
    int*   ws_cnt = (int*)(ws_u + 128);                   // 1
    int*   ws_list = ws_cnt + 1;                          // NQ

    float* out0 = (float*)d_out;
    float* out1 = out0 + (size_t)NQ * EMBED;

    hipMemsetAsync(ws_cnt, 0, sizeof(int), stream);
    hipLaunchKernelGGL(k_uvec, dim3(1), dim3(128), 0, stream, Wout, Wproj, ws_u);
    hipLaunchKernelGGL(k_prep, dim3(NPB_A + NPB_B), dim3(256), 0, stream,
                       value, Wval, bval, query, Woff, boff, Wattn, battn,
                       ws_u, ws_vh, ws_g, ws_off, ws_aw);
    hipLaunchKernelGGL(k_main, dim3(NQ), dim3(256), 0, stream,
                       query, refp, ws_off, ws_aw, ws_vh, ws_u, Wout, bout,
                       out0, out1, ws_cnt, ws_list);
    hipLaunchKernelGGL(k_fix, dim3(256), dim3(64), 0, stream,
                       refp, ws_off, ws_aw, ws_g, ws_cnt, ws_list, out1);
}

// Round 7
// 319.758 us; speedup vs baseline: 1.2213x; 1.1657x over previous
//
#include <hip/hip_runtime.h>
#include <hip/hip_fp16.h>
#include <math.h>

#define EMBED   128
#define NHEADS  8
#define NPOINTS 4
#define HD      16
#define HSP     51
#define WSP     102
#define NPIX    (HSP * WSP)   // 5202
#define NQ      10000
#define NLVL    50
#define TAU     2.0e-4f       // argmax ambiguity threshold (fp16 logit err ~2e-5)

// ---------------------------------------------------------------------------
// u = W_out @ W_proj (128 floats) + zero the fixup counter (replaces memset).
// ---------------------------------------------------------------------------
__global__ __launch_bounds__(128) void k_uvec(const float* __restrict__ Wout,
                                              const float* __restrict__ Wproj,
                                              float* __restrict__ u,
                                              int* __restrict__ cnt) {
    const int c = threadIdx.x;
    if (c == 0) *cnt = 0;
    float acc = 0.f;
#pragma unroll 8
    for (int d = 0; d < EMBED; ++d)
        acc = fmaf(Wout[(size_t)c * EMBED + d], Wproj[d], acc);
    u[c] = acc;
}

// ---------------------------------------------------------------------------
// Fused prep kernel. 256 threads/block:
//   blocks [0, 2601)         : value projection -> fp16 per-head layout + g-field
//   blocks [2601, 2601+5000) : offsets + attention softmax (2 queries/block)
// g[h][pix] = sum_c v_f32[h][pix][c] * u[h*16+c]  (f32 — exact logit source)
// ---------------------------------------------------------------------------
#define NPB_A ((NPIX + 1) / 2)   // 2601
#define NPB_B (NQ / 2)           // 5000

__global__ __launch_bounds__(256) void k_prep(
    const float* __restrict__ value,
    const float* __restrict__ Wv,
    const float* __restrict__ bv,
    const float* __restrict__ query,
    const float* __restrict__ Woff,
    const float* __restrict__ boff,
    const float* __restrict__ Wattn,
    const float* __restrict__ battn,
    const float* __restrict__ uvec,
    __half* __restrict__ vh,        // (8, NPIX, 16) fp16
    float* __restrict__ gfield,     // (8, NPIX) f32
    float* __restrict__ off_out,
    float* __restrict__ aw_out) {
    const int b = blockIdx.x;
    const int t = threadIdx.x;
    const int unit = t >> 7;      // 0 or 1
    const int tt = t & 127;

    if (b < NPB_A) {  // ---- value projection + fp16 pack + g ----
        __shared__ float vrow[2][EMBED];
        __shared__ float gprod[2][EMBED];
        const int pix = b * 2 + unit;
        vrow[unit][tt] = value[(size_t)pix * EMBED + tt];
        __syncthreads();
        float acc = bv[tt];
        const float* vr = vrow[unit];
#pragma unroll 8
        for (int k = 0; k < EMBED; ++k)
            acc = fmaf(vr[k], Wv[(size_t)k * EMBED + tt], acc);
        const int h = tt >> 4, c = tt & 15;
        vh[((size_t)h * NPIX + pix) * HD + c] = __float2half(acc);
        gprod[unit][tt] = acc * uvec[tt];
        __syncthreads();
        if (t < 16) {
            const int u2 = t >> 3, h2 = t & 7;
            float s = 0.f;
#pragma unroll
            for (int c2 = 0; c2 < HD; ++c2)
                s += gprod[u2][h2 * HD + c2];
            gfield[(size_t)h2 * NPIX + b * 2 + u2] = s;
        }
    } else {  // ---- offsets + attention ----
        const int q = (b - NPB_A) * 2 + unit;
        __shared__ float qrow[2][EMBED];
        __shared__ float attn[2][32];
        qrow[unit][tt] = query[(size_t)q * EMBED + tt];
        __syncthreads();
        const float* qr = qrow[unit];
        if (tt < 64) {
            float acc = boff[tt];
#pragma unroll 8
            for (int k = 0; k < EMBED; ++k)
                acc = fmaf(qr[k], Woff[(size_t)k * 64 + tt], acc);
            off_out[(size_t)q * 64 + tt] = acc;
        } else if (tt < 96) {
            const int j = tt - 64;
            float acc = battn[j];
#pragma unroll 8
            for (int k = 0; k < EMBED; ++k)
                acc = fmaf(qr[k], Wattn[(size_t)k * 32 + j], acc);
            attn[unit][j] = acc;
        }
        __syncthreads();
        if (tt < NHEADS) {
            const float a0 = attn[unit][tt * 4 + 0], a1 = attn[unit][tt * 4 + 1];
            const float a2 = attn[unit][tt * 4 + 2], a3 = attn[unit][tt * 4 + 3];
            const float mx = fmaxf(fmaxf(a0, a1), fmaxf(a2, a3));
            const float e0 = __expf(a0 - mx), e1 = __expf(a1 - mx);
            const float e2 = __expf(a2 - mx), e3 = __expf(a3 - mx);
            const float inv = 1.f / (e0 + e1 + e2 + e3);
            aw_out[(size_t)q * 32 + tt * 4 + 0] = e0 * inv;
            aw_out[(size_t)q * 32 + tt * 4 + 1] = e1 * inv;
            aw_out[(size_t)q * 32 + tt * 4 + 2] = e2 * inv;
            aw_out[(size_t)q * 32 + tt * 4 + 3] = e3 * inv;
        }
    }
}

// ---------------------------------------------------------------------------
// Main kernel. 1 query per 256-block, 4 waves/query (levels l = 4i+w).
// Lane = h*8 + yc*4 + xc*2 + c8: one 16B fp16 load per (lane, point) covers
// all 4 corners x 16 ch x 8 heads per wave instruction (4 vmem inst/level).
// launch_bounds(256,4): R6's (256,8) forced a 32-VGPR allocation and spilled
// the ~50-float live state to scratch (WRITE_SIZE 5->139 MB). 128-VGPR cap
// removes the spills; HW still co-schedules ~8 blocks/CU at ~64 VGPR.
// ---------------------------------------------------------------------------
__global__ __launch_bounds__(256, 4) void k_main(
    const float* __restrict__ query,
    const float* __restrict__ refp,   // (NLVL, NQ, 2)
    const float* __restrict__ voff,   // (NQ, 8, 4, 2)
    const float* __restrict__ vaw,    // (NQ, 8, 4)
    const __half* __restrict__ vh,    // (8, NPIX, 16) fp16
    const float* __restrict__ uvec,   // (128)
    const float* __restrict__ Wout,   // (128, 128)
    const float* __restrict__ bout,   // (128)
    float* __restrict__ out0,         // (NQ, 128)
    float* __restrict__ out1,         // (NQ)
    int* __restrict__ cnt,
    int* __restrict__ list) {
    const int t = threadIdx.x;
    const int w = t >> 6;             // wave 0..3
    const int lane = t & 63;
    const int h  = lane >> 3;
    const int yc = (lane >> 2) & 1;
    const int xc = (lane >> 1) & 1;
    const int c8 = lane & 1;
    const int q = blockIdx.x;

    __shared__ float  s_rpy[NLVL];
    __shared__ float4 s_pub[3][32];   // [wave-1][h*4 + c8*2 + k]
    __shared__ float  s_ms[3], s_m2s[3], s_zs[3];
    __shared__ int    s_bs[3];
    __shared__ float4 s_sv[32];

    if (t < NLVL) s_rpy[t] = refp[((size_t)t * NQ + q) * 2 + 1];

    const float4 o01 = *(const float4*)(voff + (size_t)q * 64 + h * 8);
    const float4 o23 = *(const float4*)(voff + (size_t)q * 64 + h * 8 + 4);
    const float4 aw4 = *(const float4*)(vaw + (size_t)q * 32 + h * 4);
    const float4 ua = *(const float4*)(uvec + h * 16 + c8 * 8);
    const float4 ub = *(const float4*)(uvec + h * 16 + c8 * 8 + 4);
    const float rpx = refp[(size_t)q * 2];

    const float offx[4] = {o01.x, o01.z, o23.x, o23.z};
    const float offy[4] = {o01.y, o01.w, o23.y, o23.w};
    const float aww[4]  = {aw4.x, aw4.y, aw4.z, aw4.w};

    // level-independent x state: this lane's x-corner weight (incl aw) & pixel
    float wlx[NPOINTS], oyc[NPOINTS];
    int xpix[NPOINTS];
#pragma unroll
    for (int p = 0; p < NPOINTS; ++p) {
        const float px = fmaf(rpx, (float)WSP, offx[p]) - 0.5f;
        const float fx = floorf(px);
        const float dx = px - fx;
        const int xi = (int)fx + xc;
        const float wx = xc ? dx : (1.f - dx);
        wlx[p] = ((unsigned)xi < (unsigned)WSP) ? aww[p] * wx : 0.f;
        xpix[p] = min(max(xi, 0), WSP - 1);
        oyc[p] = offy[p] - 0.5f;
    }
    const __half* vb = vh + (size_t)h * NPIX * HD + c8 * 8;

    __syncthreads();

    float a0_ = 0.f, a1_ = 0.f, a2_ = 0.f, a3_ = 0.f;
    float a4_ = 0.f, a5_ = 0.f, a6_ = 0.f, a7_ = 0.f;
    float Z = 0.f, m = -1e30f, m2 = -1e30f;
    int best = 0;

#pragma unroll 1
    for (int i = 0; i < 13; ++i) {
        const int l = 4 * i + w;
        if (l >= NLVL) break;         // wave-uniform (w)
        const float rpy = s_rpy[l];
        float s0 = 0.f, s1 = 0.f, s2 = 0.f, s3 = 0.f;
        float s4 = 0.f, s5 = 0.f, s6 = 0.f, s7 = 0.f;
#pragma unroll
        for (int p = 0; p < NPOINTS; ++p) {
            const float py = fmaf(rpy, (float)HSP, oyc[p]);
            const float fy = floorf(py);
            const float dy = py - fy;
            const int yi = (int)fy + yc;
            const float wy = yc ? dy : (1.f - dy);
            const float wv = ((unsigned)yi < (unsigned)HSP) ? wy : 0.f;
            const float wgt = wlx[p] * wv;
            const int pixel = min(max(yi, 0), HSP - 1) * WSP + xpix[p];
            const float4 raw = *(const float4*)(vb + (size_t)pixel * HD);
            const __half2* hp = (const __half2*)&raw;
            const float2 f0 = __half22float2(hp[0]);
            const float2 f1 = __half22float2(hp[1]);
            const float2 f2 = __half22float2(hp[2]);
            const float2 f3 = __half22float2(hp[3]);
            s0 = fmaf(wgt, f0.x, s0); s1 = fmaf(wgt, f0.y, s1);
            s2 = fmaf(wgt, f1.x, s2); s3 = fmaf(wgt, f1.y, s3);
            s4 = fmaf(wgt, f2.x, s4); s5 = fmaf(wgt, f2.y, s5);
            s6 = fmaf(wgt, f3.x, s6); s7 = fmaf(wgt, f3.y, s7);
        }
        // logit: dot with u, full 64-lane reduce covers corners+heads+channels
        float part = s0 * ua.x;
        part = fmaf(s1, ua.y, part);
        part = fmaf(s2, ua.z, part);
        part = fmaf(s3, ua.w, part);
        part = fmaf(s4, ub.x, part);
        part = fmaf(s5, ub.y, part);
        part = fmaf(s6, ub.z, part);
        part = fmaf(s7, ub.w, part);
#pragma unroll
        for (int d = 1; d < 64; d <<= 1)
            part += __shfl_xor(part, d, 64);
        const float e = __expf(part);
        Z += e;
        a0_ = fmaf(e, s0, a0_); a1_ = fmaf(e, s1, a1_);
        a2_ = fmaf(e, s2, a2_); a3_ = fmaf(e, s3, a3_);
        a4_ = fmaf(e, s4, a4_); a5_ = fmaf(e, s5, a5_);
        a6_ = fmaf(e, s6, a6_); a7_ = fmaf(e, s7, a7_);
        if (part > m) { m2 = m; m = part; best = l; }
        else          { m2 = fmaxf(m2, part); }
    }

    // corner-merge accumulators: xc (bit1), then yc (bit2); result in all lanes
#pragma unroll
    for (int d = 2; d <= 4; d <<= 1) {
        a0_ += __shfl_xor(a0_, d, 64); a1_ += __shfl_xor(a1_, d, 64);
        a2_ += __shfl_xor(a2_, d, 64); a3_ += __shfl_xor(a3_, d, 64);
        a4_ += __shfl_xor(a4_, d, 64); a5_ += __shfl_xor(a5_, d, 64);
        a6_ += __shfl_xor(a6_, d, 64); a7_ += __shfl_xor(a7_, d, 64);
    }

    // waves 1..3 publish; wave 0 merges
    if (w > 0) {
        if ((lane & 6) == 0) {        // one lane per (h, c8)
            const int g = h * 4 + c8 * 2;
            s_pub[w - 1][g]     = make_float4(a0_, a1_, a2_, a3_);
            s_pub[w - 1][g + 1] = make_float4(a4_, a5_, a6_, a7_);
        }
        if (lane == 0) {
            s_ms[w - 1] = m; s_m2s[w - 1] = m2;
            s_zs[w - 1] = Z; s_bs[w - 1] = best;
        }
    }
    __syncthreads();

    if (w == 0) {
        const int g = h * 4 + c8 * 2;
#pragma unroll
        for (int j = 0; j < 3; ++j) {
            const float4 pa = s_pub[j][g];
            const float4 pb = s_pub[j][g + 1];
            const float mo = s_ms[j], m2o = s_m2s[j], Zo = s_zs[j];
            const int bo = s_bs[j];
            const bool takeOther = (mo > m) || (mo == m && bo < best);
            m2 = fmaxf(fmaxf(m2, m2o), fminf(m, mo));
            best = takeOther ? bo : best;
            m = fmaxf(m, mo);
            Z += Zo;
            a0_ += pa.x; a1_ += pa.y; a2_ += pa.z; a3_ += pa.w;
            a4_ += pb.x; a5_ += pb.y; a6_ += pb.z; a7_ += pb.w;
        }
        const float inv = 1.f / Z;
        if ((lane & 6) == 0) {
            s_sv[g]     = make_float4(a0_ * inv, a1_ * inv, a2_ * inv, a3_ * inv);
            s_sv[g + 1] = make_float4(a4_ * inv, a5_ * inv, a6_ * inv, a7_ * inv);
        }
        if (lane == 0) {
            out1[q] = (float)best;
            if (m - m2 < TAU) {             // ambiguous under fp16 noise -> fixup
                const int ii = atomicAdd(cnt, 1);
                list[ii] = q;
            }
        }
        // same-wave DS ordering: s_sv writes visible to wave 0's reads below

        // epilogue: out[dp] = sum_c s[c]*Wout[c][dp] + bout[dp] + 2*query[q][dp]
        const int sub = lane & 31;
        const int half = lane >> 5;
        const int dpb = sub * 4;
        float4 r = {0.f, 0.f, 0.f, 0.f};
        if (half == 0) {
            const float4 b4 = *(const float4*)(bout + dpb);
            const float4 q4 = *(const float4*)(query + (size_t)q * EMBED + dpb);
            r.x = fmaf(2.f, q4.x, b4.x);
            r.y = fmaf(2.f, q4.y, b4.y);
            r.z = fmaf(2.f, q4.z, b4.z);
            r.w = fmaf(2.f, q4.w, b4.w);
        }
        const int cg0 = half * 16;
#pragma unroll 4
        for (int cg = cg0; cg < cg0 + 16; ++cg) {
            const float4 s4 = s_sv[cg];
            const float4 w0 = *(const float4*)(Wout + (size_t)(cg * 4 + 0) * EMBED + dpb);
            const float4 w1 = *(const float4*)(Wout + (size_t)(cg * 4 + 1) * EMBED + dpb);
            const float4 w2v = *(const float4*)(Wout + (size_t)(cg * 4 + 2) * EMBED + dpb);
            const float4 w3 = *(const float4*)(Wout + (size_t)(cg * 4 + 3) * EMBED + dpb);
            r.x = fmaf(s4.x, w0.x, r.x); r.y = fmaf(s4.x, w0.y, r.y);
            r.z = fmaf(s4.x, w0.z, r.z); r.w = fmaf(s4.x, w0.w, r.w);
            r.x = fmaf(s4.y, w1.x, r.x); r.y = fmaf(s4.y, w1.y, r.y);
            r.z = fmaf(s4.y, w1.z, r.z); r.w = fmaf(s4.y, w1.w, r.w);
            r.x = fmaf(s4.z, w2v.x, r.x); r.y = fmaf(s4.z, w2v.y, r.y);
            r.z = fmaf(s4.z, w2v.z, r.z); r.w = fmaf(s4.z, w2v.w, r.w);
            r.x = fmaf(s4.w, w3.x, r.x); r.y = fmaf(s4.w, w3.y, r.y);
            r.z = fmaf(s4.w, w3.z, r.z); r.w = fmaf(s4.w, w3.w, r.w);
        }
        {
            const float rx = __shfl_xor(r.x, 32, 64);
            const float ry = __shfl_xor(r.y, 32, 64);
            const float rz = __shfl_xor(r.z, 32, 64);
            const float rw = __shfl_xor(r.w, 32, 64);
            r.x += rx; r.y += ry; r.z += rz; r.w += rw;
        }
        if (half == 0)
            *(float4*)(out0 + (size_t)q * EMBED + dpb) = r;
    }
}

// ---------------------------------------------------------------------------
// Exact-f32 argmax fixup for flagged queries (bilinear of g == exact logit).
// ---------------------------------------------------------------------------
__global__ __launch_bounds__(64) void k_fix(
    const float* __restrict__ refp,
    const float* __restrict__ voff,
    const float* __restrict__ vaw,
    const float* __restrict__ gfield,  // (8, NPIX)
    const int* __restrict__ cnt,
    const int* __restrict__ list,
    float* __restrict__ out1) {
    const int n = *cnt;
    const int lane = threadIdx.x;
    for (int idx = blockIdx.x; idx < n; idx += gridDim.x) {
        const int q = list[idx];
        float logit = -1e30f;
        if (lane < NLVL) {
            const float rpx = refp[(size_t)q * 2];
            const float rpy = refp[((size_t)lane * NQ + q) * 2 + 1];
            float accl = 0.f;
            for (int h = 0; h < NHEADS; ++h) {
                const float4 o01 = *(const float4*)(voff + (size_t)q * 64 + h * 8);
                const float4 o23 = *(const float4*)(voff + (size_t)q * 64 + h * 8 + 4);
                const float4 aw4 = *(const float4*)(vaw + (size_t)q * 32 + h * 4);
                const float* gh = gfield + (size_t)h * NPIX;
                const float offx[4] = {o01.x, o01.z, o23.x, o23.z};
                const float offy[4] = {o01.y, o01.w, o23.y, o23.w};
                const float aww[4]  = {aw4.x, aw4.y, aw4.z, aw4.w};
#pragma unroll
                for (int p = 0; p < NPOINTS; ++p) {
                    const float px = fmaf(rpx, (float)WSP, offx[p]) - 0.5f;
                    const float py = fmaf(rpy, (float)HSP, offy[p]) - 0.5f;
                    const float fx = floorf(px), fy = floorf(py);
                    const float dx = px - fx, dy = py - fy;
                    const int x0 = (int)fx, y0 = (int)fy;
                    const float wx0 = ((unsigned)x0 < (unsigned)WSP) ? (1.f - dx) : 0.f;
                    const float wx1 = ((unsigned)(x0 + 1) < (unsigned)WSP) ? dx : 0.f;
                    const float t0 = ((unsigned)y0 < (unsigned)HSP) ? (1.f - dy) : 0.f;
                    const float t1 = ((unsigned)(y0 + 1) < (unsigned)HSP) ? dy : 0.f;
                    const int xc0 = min(max(x0, 0), WSP - 1);
                    const int xc1 = min(max(x0 + 1, 0), WSP - 1);
                    const int rb0 = min(max(y0, 0), HSP - 1) * WSP;
                    const int rb1 = min(max(y0 + 1, 0), HSP - 1) * WSP;
                    const float g00 = gh[rb0 + xc0];
                    const float g01 = gh[rb0 + xc1];
                    const float g10 = gh[rb1 + xc0];
                    const float g11 = gh[rb1 + xc1];
                    const float bil = wx0 * t0 * g00 + wx1 * t0 * g01
                                    + wx0 * t1 * g10 + wx1 * t1 * g11;
                    accl = fmaf(aww[p], bil, accl);
                }
            }
            logit = accl;
        }
        float v = logit;
        int b = lane;
#pragma unroll
        for (int d = 1; d < 64; d <<= 1) {
            const float vo = __shfl_xor(v, d, 64);
            const int bo = __shfl_xor(b, d, 64);
            if ((vo > v) || (vo == v && bo < b)) { v = vo; b = bo; }
        }
        if (lane == 0) out1[q] = (float)b;
    }
}

// ---------------------------------------------------------------------------
extern "C" void kernel_launch(void* const* d_in, const int* in_sizes, int n_in,
                              void* d_out, int out_size, void* d_ws, size_t ws_size,
                              hipStream_t stream) {
    const float* query = (const float*)d_in[0];
    const float* value = (const float*)d_in[1];
    const float* refp  = (const float*)d_in[2];
    const float* Woff  = (const float*)d_in[3];
    const float* boff  = (const float*)d_in[4];
    const float* Wattn = (const float*)d_in[5];
    const float* battn = (const float*)d_in[6];
    const float* Wval  = (const float*)d_in[7];
    const float* bval  = (const float*)d_in[8];
    const float* Wout  = (const float*)d_in[9];
    const float* bout  = (const float*)d_in[10];
    const float* Wproj = (const float*)d_in[11];
    // d_in[12] = b_proj: level-constant -> cancels in softmax/argmax, unused.

    float* ws = (float*)d_ws;
    __half* ws_vh = (__half*)ws;                          // 8*5202*16 halves
    float* ws_g   = ws + ((size_t)NHEADS * NPIX * HD + 1) / 2;  // 8*5202 f
    float* ws_off = ws_g + (size_t)NHEADS * NPIX;         // NQ*64
    float* ws_aw  = ws_off + (size_t)NQ * 64;             // NQ*32
    float* ws_u   = ws_aw + (size_t)NQ * 32;              // 128
    int*   ws_cnt = (int*)(ws_u + 128);                   // 1
    int*   ws_list = ws_cnt + 1;                          // NQ

    float* out0 = (float*)d_out;
    float* out1 = out0 + (size_t)NQ * EMBED;

    hipLaunchKernelGGL(k_uvec, dim3(1), dim3(128), 0, stream,
                       Wout, Wproj, ws_u, ws_cnt);
    hipLaunchKernelGGL(k_prep, dim3(NPB_A + NPB_B), dim3(256), 0, stream,
                       value, Wval, bval, query, Woff, boff, Wattn, battn,
                       ws_u, ws_vh, ws_g, ws_off, ws_aw);
    hipLaunchKernelGGL(k_main, dim3(NQ), dim3(256), 0, stream,
                       query, refp, ws_off, ws_aw, ws_vh, ws_u, Wout, bout,
                       out0, out1, ws_cnt, ws_list);
    hipLaunchKernelGGL(k_fix, dim3(256), dim3(64), 0, stream,
                       refp, ws_off, ws_aw, ws_g, ws_cnt, ws_list, out1);
}